// Round 7
// baseline (416.121 us; speedup 1.0000x reference)
//
#include <hip/hip_runtime.h>

#define NN   50000
#define NE   800000
#define HID  128
#define OUTD 40
#define DEG_BLKS ((NE + 255) / 256)   // 3125
#define LIN_BLKS ((NN + 127) / 128)   // 391

typedef float f32x4  __attribute__((ext_vector_type(4)));
typedef int   i32x4  __attribute__((ext_vector_type(4)));
typedef short bf16x8 __attribute__((ext_vector_type(8)));

// ---------- helpers ----------
__device__ __forceinline__ f32x4 mfma(bf16x8 a, bf16x8 b, f32x4 c) {
  return __builtin_amdgcn_mfma_f32_16x16x32_bf16(a, b, c, 0, 0, 0);
}
__device__ __forceinline__ unsigned short f2bf(float f) {
  unsigned u = __builtin_bit_cast(unsigned, f);
  u += 0x7fffu + ((u >> 16) & 1u);
  return (unsigned short)(u >> 16);
}
__device__ __forceinline__ unsigned pack2(float lo, float hi) {
  return (unsigned)f2bf(lo) | ((unsigned)f2bf(hi) << 16);
}
__device__ __forceinline__ float bflo(unsigned v){ return __builtin_bit_cast(float, v << 16); }
__device__ __forceinline__ float bfhi(unsigned v){ return __builtin_bit_cast(float, v & 0xffff0000u); }
__device__ __forceinline__ void acc_u2(uint2 v, float& x0, float& x1, float& x2, float& x3) {
  x0 += bflo(v.x); x1 += bfhi(v.x); x2 += bflo(v.y); x3 += bfhi(v.y);
}

// ---------- weight prep: transpose + bf16 cast into ws; also zeros deg ----------
// wt layout: m=0 WtIn, m=1..3 WtL[i], m=4..6 WtR[i], m=7 WtC1, then WtC2 [48][128]
__global__ void k_prep(const float* __restrict__ Win, const float* __restrict__ Wl,
                       const float* __restrict__ Wr, const float* __restrict__ Wc1,
                       const float* __restrict__ Wc2, unsigned short* __restrict__ wt,
                       int* __restrict__ deg) {
  int idx = blockIdx.x * 256 + threadIdx.x;
  if (idx < NN) deg[idx] = 0;  // folded memset
  const int NMAIN = 8 * 16384;
  if (idx >= NMAIN + 48 * 128) return;
  float v;
  if (idx < NMAIN) {
    int m = idx >> 14, rem = idx & 16383;
    int n = rem >> 7, k = rem & 127;
    const float* s;
    if (m == 0) s = Win;
    else if (m <= 3) s = Wl + (m - 1) * 16384;
    else if (m <= 6) s = Wr + (m - 4) * 16384;
    else s = Wc1;
    v = s[k * 128 + n];
  } else {
    int rem = idx - NMAIN;
    int n = rem >> 7, k = rem & 127;
    v = (n < OUTD) ? Wc2[k * OUTD + n] : 0.f;
  }
  wt[idx] = f2bf(v);
}

// ---------- lin_in body (shared by fused kernel) ----------
__device__ __forceinline__ void lin_in_body(int bid, const float* __restrict__ x,
                                            const unsigned short* __restrict__ Wt,
                                            const float* __restrict__ bias,
                                            unsigned short* __restrict__ hout) {
  const int lane = threadIdx.x & 63, w = threadIdx.x >> 6;
  const int wr = w >> 1, wc = w & 1;
  const int r15 = lane & 15, khi = lane >> 4;
  const int mbase = bid * 128 + wr * 64, nbase = wc * 64;
  f32x4 acc[4][4] = {};
#pragma unroll
  for (int ks = 0; ks < 4; ++ks) {
    const int kk = ks * 32 + khi * 8;
    bf16x8 af[4], bq[4];
#pragma unroll
    for (int i = 0; i < 4; i++) {
      int row = mbase + i * 16 + r15; row = row < NN ? row : NN - 1;
      const f32x4* p = (const f32x4*)(x + row * HID + kk);
      f32x4 lo = p[0], hi = p[1];
      i32x4 t;
      t[0] = pack2(lo[0], lo[1]); t[1] = pack2(lo[2], lo[3]);
      t[2] = pack2(hi[0], hi[1]); t[3] = pack2(hi[2], hi[3]);
      af[i] = __builtin_bit_cast(bf16x8, t);
    }
#pragma unroll
    for (int j = 0; j < 4; j++) {
      int col = nbase + j * 16 + r15;
      bq[j] = *(const bf16x8*)(Wt + col * HID + kk);
    }
#pragma unroll
    for (int i = 0; i < 4; i++)
#pragma unroll
      for (int j = 0; j < 4; j++) acc[i][j] = mfma(af[i], bq[j], acc[i][j]);
  }
  float b4[4];
#pragma unroll
  for (int j = 0; j < 4; j++) b4[j] = bias[nbase + j * 16 + r15];
#pragma unroll
  for (int i = 0; i < 4; i++) {
    const int rb = mbase + i * 16 + khi * 4;
#pragma unroll
    for (int e = 0; e < 4; e++) {
      const int r = rb + e;
      if (r < NN) {
#pragma unroll
        for (int j = 0; j < 4; j++)
          hout[r * HID + nbase + j * 16 + r15] = f2bf(acc[i][j][e] + b4[j]);
      }
    }
  }
}

// ---------- fused: deg count (+pos) || h0 = x@W_in+b_in ----------
__global__ __launch_bounds__(256) void k_deg_lin(const int* __restrict__ dst,
                                                 int* __restrict__ deg, int* __restrict__ pos,
                                                 const float* __restrict__ x,
                                                 const unsigned short* __restrict__ Wt,
                                                 const float* __restrict__ bias,
                                                 unsigned short* __restrict__ hout) {
  if (blockIdx.x < DEG_BLKS) {
    int i = blockIdx.x * 256 + threadIdx.x;
    if (i < NE) pos[i] = atomicAdd(&deg[dst[i]], 1);
  } else {
    lin_in_body(blockIdx.x - DEG_BLKS, x, Wt, bias, hout);
  }
}

// ---------- single-workgroup scan: deg -> offs (exclusive), dinv ----------
__global__ __launch_bounds__(1024) void k_scan_all(const int* __restrict__ deg,
                                                   int* __restrict__ offs,
                                                   float* __restrict__ dinv) {
  __shared__ int part[1024];
  const int t = threadIdx.x;
  const int CH = (NN + 1023) / 1024;  // 49
  const int base = t * CH;
  int sum = 0;
  for (int i = 0; i < CH; ++i) {
    int idx = base + i;
    if (idx < NN) sum += deg[idx];
  }
  part[t] = sum;
  __syncthreads();
  for (int o = 1; o < 1024; o <<= 1) {
    int xv = (t >= o) ? part[t - o] : 0;
    __syncthreads(); part[t] += xv; __syncthreads();
  }
  int running = part[t] - sum;  // exclusive
  for (int i = 0; i < CH; ++i) {
    int idx = base + i;
    if (idx < NN) {
      int d = deg[idx];
      offs[idx] = running;
      dinv[idx] = 1.0f / (float)(d > 0 ? d : 1);
      running += d;
    }
  }
  if (t == 0) offs[NN] = NE;
}

// no atomics: position precomputed in k_deg_lin
__global__ void k_fill(const int* __restrict__ src, const int* __restrict__ dst,
                       const int* __restrict__ pos, const int* __restrict__ offs,
                       int* __restrict__ csr) {
  int i = blockIdx.x * blockDim.x + threadIdx.x;
  if (i < NE) {
    csr[offs[dst[i]] + pos[i]] = src[i];
  }
}

// ---------- aggregation: half-wave per row, 2-deep software pipeline ----------
// Batch = 8 rows (4 uint2 loads, 2 rows/load). While batch b accumulates,
// batch b+1's h-loads are in flight and batch b+2's csr indices are loading.
__global__ __launch_bounds__(256, 6) void k_agg(const unsigned short* __restrict__ h,
                                                const int* __restrict__ csr,
                                                const int* __restrict__ offs,
                                                const float* __restrict__ dinv,
                                                unsigned short* __restrict__ agg) {
  const int lane = threadIdx.x & 63;
  const int l31 = lane & 31;
  const int hi = lane >> 5;
  int gw = (blockIdx.x * blockDim.x + threadIdx.x) >> 6;
  int nw = (gridDim.x * blockDim.x) >> 6;
  const uint2* h2 = (const uint2*)h;  // row stride = 32 uint2 (256B)
  uint2* ag2 = (uint2*)agg;
  for (int n = gw; n < NN; n += nw) {
    const int s = offs[n], e = offs[n + 1];
    const int nb = (e - s) >> 3;  // full 8-row batches
    float p0=0,p1=0,p2=0,p3=0, q0=0,q1=0,q2=0,q3=0;
    float u0=0,u1=0,u2=0,u3=0, w0=0,w1=0,w2=0,w3=0;
    int ia0=0,ia1=0,ia2=0,ia3=0, ib0=0,ib1=0,ib2=0,ib3=0;
    uint2 va0,va1,va2,va3, vb0,vb1,vb2,vb3;
    if (nb > 0) {  // batch 0 idx + data
      ia0=csr[s+0+hi]; ia1=csr[s+2+hi]; ia2=csr[s+4+hi]; ia3=csr[s+6+hi];
      va0=h2[ia0*32+l31]; va1=h2[ia1*32+l31]; va2=h2[ia2*32+l31]; va3=h2[ia3*32+l31];
    }
    if (nb > 1) {  // batch 1 idx + data
      int b1 = s + 8;
      ib0=csr[b1+0+hi]; ib1=csr[b1+2+hi]; ib2=csr[b1+4+hi]; ib3=csr[b1+6+hi];
      vb0=h2[ib0*32+l31]; vb1=h2[ib1*32+l31]; vb2=h2[ib2*32+l31]; vb3=h2[ib3*32+l31];
    }
    if (nb > 2) {  // batch 2 idx (for va refill)
      int b2 = s + 16;
      ia0=csr[b2+0+hi]; ia1=csr[b2+2+hi]; ia2=csr[b2+4+hi]; ia3=csr[b2+6+hi];
    }
    if (nb > 3) {  // batch 3 idx (for vb refill)
      int b3 = s + 24;
      ib0=csr[b3+0+hi]; ib1=csr[b3+2+hi]; ib2=csr[b3+4+hi]; ib3=csr[b3+6+hi];
    }
    int b = 0;
    for (; b + 2 <= nb; b += 2) {
      // consume batch b (va); refill va with batch b+2; load idx batch b+4
      acc_u2(va0, p0,p1,p2,p3); acc_u2(va1, q0,q1,q2,q3);
      acc_u2(va2, u0,u1,u2,u3); acc_u2(va3, w0,w1,w2,w3);
      if (b + 2 < nb) {
        va0=h2[ia0*32+l31]; va1=h2[ia1*32+l31]; va2=h2[ia2*32+l31]; va3=h2[ia3*32+l31];
      }
      if (b + 4 < nb) {
        int kk = s + ((b + 4) << 3);
        ia0=csr[kk+0+hi]; ia1=csr[kk+2+hi]; ia2=csr[kk+4+hi]; ia3=csr[kk+6+hi];
      }
      // consume batch b+1 (vb); refill vb with batch b+3; load idx batch b+5
      acc_u2(vb0, p0,p1,p2,p3); acc_u2(vb1, q0,q1,q2,q3);
      acc_u2(vb2, u0,u1,u2,u3); acc_u2(vb3, w0,w1,w2,w3);
      if (b + 3 < nb) {
        vb0=h2[ib0*32+l31]; vb1=h2[ib1*32+l31]; vb2=h2[ib2*32+l31]; vb3=h2[ib3*32+l31];
      }
      if (b + 5 < nb) {
        int kk = s + ((b + 5) << 3);
        ib0=csr[kk+0+hi]; ib1=csr[kk+2+hi]; ib2=csr[kk+4+hi]; ib3=csr[kk+6+hi];
      }
    }
    if (b < nb) {  // odd batch count: last full batch sits in va
      acc_u2(va0, p0,p1,p2,p3); acc_u2(va1, q0,q1,q2,q3);
      acc_u2(va2, u0,u1,u2,u3); acc_u2(va3, w0,w1,w2,w3);
    }
    int k = s + (nb << 3);
    for (; k + 2 <= e; k += 2) {
      int r = csr[k + hi];
      uint2 v = h2[r * 32 + l31];
      acc_u2(v, p0,p1,p2,p3);
    }
    if (k < e) {  // odd last row: both halves load, only low half accumulates
      int r = csr[k];
      uint2 v = h2[r * 32 + l31];
      if (hi == 0) acc_u2(v, p0,p1,p2,p3);
    }
    float s0 = (p0 + q0) + (u0 + w0), s1 = (p1 + q1) + (u1 + w1);
    float s2 = (p2 + q2) + (u2 + w2), s3 = (p3 + q3) + (u3 + w3);
    s0 += __shfl_xor(s0, 32); s1 += __shfl_xor(s1, 32);
    s2 += __shfl_xor(s2, 32); s3 += __shfl_xor(s3, 32);
    float di = dinv[n];
    if (hi == 0) {
      uint2 o;
      o.x = pack2(s0 * di, s1 * di);
      o.y = pack2(s2 * di, s3 * di);
      ag2[n * 32 + l31] = o;
    }
  }
}

// ---------- GEMM: h_new = relu(h @ Wl + agg @ Wr + bl) (bf16 in/out) ----------
__global__ __launch_bounds__(256) void k_layer(const unsigned short* __restrict__ hp,
                                               const unsigned short* __restrict__ ag,
                                               const unsigned short* __restrict__ WtL,
                                               const unsigned short* __restrict__ WtR,
                                               const float* __restrict__ bias,
                                               unsigned short* __restrict__ hout) {
  const int lane = threadIdx.x & 63, w = threadIdx.x >> 6;
  const int wr = w >> 1, wc = w & 1;
  const int r15 = lane & 15, khi = lane >> 4;
  const int mbase = blockIdx.x * 128 + wr * 64, nbase = wc * 64;
  f32x4 acc[4][4] = {};
#pragma unroll
  for (int ph = 0; ph < 2; ++ph) {
    const unsigned short* A = ph ? ag : hp;
    const unsigned short* B = ph ? WtR : WtL;
#pragma unroll
    for (int ks = 0; ks < 4; ++ks) {
      const int kk = ks * 32 + khi * 8;
      bf16x8 af[4], bq[4];
#pragma unroll
      for (int i = 0; i < 4; i++) {
        int row = mbase + i * 16 + r15; row = row < NN ? row : NN - 1;
        af[i] = *(const bf16x8*)(A + row * HID + kk);
      }
#pragma unroll
      for (int j = 0; j < 4; j++) {
        int col = nbase + j * 16 + r15;
        bq[j] = *(const bf16x8*)(B + col * HID + kk);
      }
#pragma unroll
      for (int i = 0; i < 4; i++)
#pragma unroll
        for (int j = 0; j < 4; j++) acc[i][j] = mfma(af[i], bq[j], acc[i][j]);
    }
  }
  float b4[4];
#pragma unroll
  for (int j = 0; j < 4; j++) b4[j] = bias[nbase + j * 16 + r15];
#pragma unroll
  for (int i = 0; i < 4; i++) {
    const int rb = mbase + i * 16 + khi * 4;
#pragma unroll
    for (int e = 0; e < 4; e++) {
      const int r = rb + e;
      if (r < NN) {
#pragma unroll
        for (int j = 0; j < 4; j++) {
          float v = acc[i][j][e] + b4[j];
          v = fmaxf(v, 0.f);
          hout[r * HID + nbase + j * 16 + r15] = f2bf(v);
        }
      }
    }
  }
}

// ---------- classifier: out = relu((h1+h2+h3)@Wc1+bc1)@Wc2+bc2 ----------
__global__ __launch_bounds__(256) void k_cls(const unsigned short* __restrict__ h1,
                                             const unsigned short* __restrict__ h2,
                                             const unsigned short* __restrict__ h3,
                                             const unsigned short* __restrict__ WtC1,
                                             const float* __restrict__ bc1,
                                             const unsigned short* __restrict__ WtC2,
                                             const float* __restrict__ bc2,
                                             float* __restrict__ out) {
  __shared__ unsigned short hc[128 * 136];  // padded row stride 136
  const int lane = threadIdx.x & 63, w = threadIdx.x >> 6;
  const int wr = w >> 1, wc = w & 1;
  const int r15 = lane & 15, khi = lane >> 4;
  const int mbase = blockIdx.x * 128 + wr * 64, nbase = wc * 64;
  // stage 1: hc = relu((h1+h2+h3) @ Wc1 + bc1)
  {
    f32x4 acc[4][4] = {};
#pragma unroll
    for (int ks = 0; ks < 4; ++ks) {
      const int kk = ks * 32 + khi * 8;
      bf16x8 af[4], bq[4];
#pragma unroll
      for (int i = 0; i < 4; i++) {
        int row = mbase + i * 16 + r15; row = row < NN ? row : NN - 1;
        i32x4 u = *(const i32x4*)(h1 + row * HID + kk);
        i32x4 v = *(const i32x4*)(h2 + row * HID + kk);
        i32x4 q = *(const i32x4*)(h3 + row * HID + kk);
        i32x4 t;
#pragma unroll
        for (int c = 0; c < 4; c++) {
          unsigned uu = u[c], vv = v[c], qq = q[c];
          t[c] = pack2(bflo(uu) + bflo(vv) + bflo(qq), bfhi(uu) + bfhi(vv) + bfhi(qq));
        }
        af[i] = __builtin_bit_cast(bf16x8, t);
      }
#pragma unroll
      for (int j = 0; j < 4; j++) {
        int col = nbase + j * 16 + r15;
        bq[j] = *(const bf16x8*)(WtC1 + col * HID + kk);
      }
#pragma unroll
      for (int i = 0; i < 4; i++)
#pragma unroll
        for (int j = 0; j < 4; j++) acc[i][j] = mfma(af[i], bq[j], acc[i][j]);
    }
    float b4[4];
#pragma unroll
    for (int j = 0; j < 4; j++) b4[j] = bc1[nbase + j * 16 + r15];
#pragma unroll
    for (int i = 0; i < 4; i++) {
      const int rT = wr * 64 + i * 16 + khi * 4;
#pragma unroll
      for (int e = 0; e < 4; e++) {
#pragma unroll
        for (int j = 0; j < 4; j++) {
          float v = fmaxf(acc[i][j][e] + b4[j], 0.f);
          hc[(rT + e) * 136 + nbase + j * 16 + r15] = f2bf(v);
        }
      }
    }
  }
  __syncthreads();
  // stage 2: out = hc @ Wc2 + bc2
  {
    f32x4 a2[2][3] = {};
#pragma unroll
    for (int ks = 0; ks < 4; ++ks) {
      const int kk = ks * 32 + khi * 8;
      bf16x8 af[2], bq[3];
#pragma unroll
      for (int i = 0; i < 2; i++) {
        int rT = w * 32 + i * 16 + r15;
        af[i] = *(const bf16x8*)&hc[rT * 136 + kk];
      }
#pragma unroll
      for (int j = 0; j < 3; j++) {
        int col = j * 16 + r15;
        bq[j] = *(const bf16x8*)(WtC2 + col * HID + kk);
      }
#pragma unroll
      for (int i = 0; i < 2; i++)
#pragma unroll
        for (int j = 0; j < 3; j++) a2[i][j] = mfma(af[i], bq[j], a2[i][j]);
    }
#pragma unroll
    for (int j = 0; j < 3; j++) {
      const int col = j * 16 + r15;
      const float b = (col < OUTD) ? bc2[col] : 0.f;
#pragma unroll
      for (int i = 0; i < 2; i++) {
        const int rT = w * 32 + i * 16 + khi * 4;
#pragma unroll
        for (int e = 0; e < 4; e++) {
          const int gr = blockIdx.x * 128 + rT + e;
          if (gr < NN && col < OUTD) out[gr * OUTD + col] = a2[i][j][e] + b;
        }
      }
    }
  }
}

// ---------- launch ----------
extern "C" void kernel_launch(void* const* d_in, const int* in_sizes, int n_in,
                              void* d_out, int out_size, void* d_ws, size_t ws_size,
                              hipStream_t stream) {
  (void)in_sizes; (void)n_in; (void)out_size; (void)ws_size;
  const float* x   = (const float*)d_in[0];
  const int*   ei  = (const int*)d_in[1];
  const float* Win = (const float*)d_in[2];
  const float* bin = (const float*)d_in[3];
  const float* Wl  = (const float*)d_in[4];
  const float* Wr  = (const float*)d_in[5];
  const float* bl  = (const float*)d_in[6];
  const float* Wc1 = (const float*)d_in[7];
  const float* bc1 = (const float*)d_in[8];
  const float* Wc2 = (const float*)d_in[9];
  const float* bc2 = (const float*)d_in[10];
  float* out = (float*)d_out;

  char* ws = (char*)d_ws;
  size_t off = 0;
  auto take = [&](size_t bytes) -> char* {
    char* p = ws + off; off = (off + bytes + 255) & ~(size_t)255; return p;
  };
  int* deg        = (int*)take((size_t)NN * 4);
  int* offs       = (int*)take((size_t)(NN + 1) * 4);
  int* pos        = (int*)take((size_t)NE * 4);
  float* dinv     = (float*)take((size_t)NN * 4);
  int* csr        = (int*)take((size_t)NE * 4);
  unsigned short* wt  = (unsigned short*)take((size_t)(8 * 16384 + 48 * 128) * 2);
  unsigned short* h0  = (unsigned short*)take((size_t)NN * HID * 2);
  unsigned short* h1  = (unsigned short*)take((size_t)NN * HID * 2);
  unsigned short* h2  = (unsigned short*)take((size_t)NN * HID * 2);
  unsigned short* h3  = (unsigned short*)take((size_t)NN * HID * 2);
  unsigned short* agg = (unsigned short*)take((size_t)NN * HID * 2);

  const int* esrc = ei;
  const int* edst = ei + NE;

  k_prep<<<(8 * 16384 + 48 * 128 + 255) / 256, 256, 0, stream>>>(Win, Wl, Wr, Wc1, Wc2, wt, deg);
  k_deg_lin<<<DEG_BLKS + LIN_BLKS, 256, 0, stream>>>(edst, deg, pos, x, wt, bin, h0);
  k_scan_all<<<1, 1024, 0, stream>>>(deg, offs, dinv);
  k_fill<<<(NE + 255) / 256, 256, 0, stream>>>(esrc, edst, pos, offs, csr);

  unsigned short* hs[4] = {h0, h1, h2, h3};
  for (int i = 0; i < 3; i++) {
    k_agg<<<2048, 256, 0, stream>>>(hs[i], csr, offs, dinv, agg);
    k_layer<<<LIN_BLKS, 256, 0, stream>>>(hs[i], agg, wt + (1 + i) * 16384,
                                          wt + (4 + i) * 16384, bl + i * HID, hs[i + 1]);
  }
  k_cls<<<LIN_BLKS, 256, 0, stream>>>(h1, h2, h3, wt + 7 * 16384, bc1,
                                      wt + 8 * 16384, bc2, out);
}

// Round 8
// 376.304 us; speedup vs baseline: 1.1058x; 1.1058x over previous
//
#include <hip/hip_runtime.h>

#define NN   50000
#define NE   800000
#define HID  128
#define OUTD 40
#define NBLK 196  // ceil(NN/256)

typedef float f32x4  __attribute__((ext_vector_type(4)));
typedef int   i32x4  __attribute__((ext_vector_type(4)));
typedef short bf16x8 __attribute__((ext_vector_type(8)));

// ---------- helpers ----------
__device__ __forceinline__ f32x4 mfma(bf16x8 a, bf16x8 b, f32x4 c) {
  return __builtin_amdgcn_mfma_f32_16x16x32_bf16(a, b, c, 0, 0, 0);
}
__device__ __forceinline__ unsigned short f2bf(float f) {
  unsigned u = __builtin_bit_cast(unsigned, f);
  u += 0x7fffu + ((u >> 16) & 1u);
  return (unsigned short)(u >> 16);
}
__device__ __forceinline__ unsigned pack2(float lo, float hi) {
  return (unsigned)f2bf(lo) | ((unsigned)f2bf(hi) << 16);
}
__device__ __forceinline__ float bflo(unsigned v){ return __builtin_bit_cast(float, v << 16); }
__device__ __forceinline__ float bfhi(unsigned v){ return __builtin_bit_cast(float, v & 0xffff0000u); }

// h buffers are column-blocked: 4 blocks of 32 cols, so the per-pass gather
// working set (NN*32 cols bf16 = 3.2MB) fits a 4MiB per-XCD L2.
// bf16 index of (row, col):
__device__ __forceinline__ int haddr(int row, int col) {
  return (col >> 5) * (NN * 32) + row * 32 + (col & 31);
}

// ---------- CSR build ----------
__global__ void k_deg(const int* __restrict__ dst, int* __restrict__ deg,
                      int* __restrict__ pos) {
  int i = blockIdx.x * blockDim.x + threadIdx.x;
  if (i < NE) pos[i] = atomicAdd(&deg[dst[i]], 1);
}

__global__ void k_blocksum(const int* __restrict__ deg, int* __restrict__ bsum) {
  __shared__ int s[256];
  int t = threadIdx.x, i = blockIdx.x * 256 + t;
  s[t] = (i < NN) ? deg[i] : 0;
  __syncthreads();
  for (int o = 128; o > 0; o >>= 1) { if (t < o) s[t] += s[t + o]; __syncthreads(); }
  if (t == 0) bsum[blockIdx.x] = s[0];
}

// fused: per-block exclusive base (reduce bsum[0..blockIdx)) + local scan
__global__ void k_scan3(const int* __restrict__ deg, const int* __restrict__ bsum,
                        int* __restrict__ offs, float* __restrict__ dinv) {
  __shared__ int sb[256];
  __shared__ int s[256];
  int t = threadIdx.x, i = blockIdx.x * 256 + t;
  sb[t] = (t < NBLK && t < blockIdx.x) ? bsum[t] : 0;
  int v = (i < NN) ? deg[i] : 0;
  s[t] = v;
  __syncthreads();
  for (int o = 128; o > 0; o >>= 1) { if (t < o) sb[t] += sb[t + o]; __syncthreads(); }
  for (int o = 1; o < 256; o <<= 1) {
    int x = (t >= o) ? s[t - o] : 0;
    __syncthreads(); s[t] += x; __syncthreads();
  }
  int off = sb[0] + s[t] - v;  // exclusive within-array offset
  if (i < NN) {
    offs[i] = off;
    dinv[i] = 1.0f / (float)(v > 0 ? v : 1);
  }
  if (i == 0) offs[NN] = NE;
}

// no atomics: position precomputed in k_deg
__global__ void k_fill(const int* __restrict__ src, const int* __restrict__ dst,
                       const int* __restrict__ pos, const int* __restrict__ offs,
                       int* __restrict__ csr) {
  int i = blockIdx.x * blockDim.x + threadIdx.x;
  if (i < NE) {
    csr[offs[dst[i]] + pos[i]] = src[i];
  }
}

// ---------- weight prep: transpose + bf16 cast into ws; also zeros deg ----------
// wt layout: m=0 WtIn, m=1..3 WtL[i], m=4..6 WtR[i], m=7 WtC1, then WtC2 [48][128]
__global__ void k_prep(const float* __restrict__ Win, const float* __restrict__ Wl,
                       const float* __restrict__ Wr, const float* __restrict__ Wc1,
                       const float* __restrict__ Wc2, unsigned short* __restrict__ wt,
                       int* __restrict__ deg) {
  int idx = blockIdx.x * 256 + threadIdx.x;
  if (idx < NN) deg[idx] = 0;  // folded memset
  const int NMAIN = 8 * 16384;
  if (idx >= NMAIN + 48 * 128) return;
  float v;
  if (idx < NMAIN) {
    int m = idx >> 14, rem = idx & 16383;
    int n = rem >> 7, k = rem & 127;
    const float* s;
    if (m == 0) s = Win;
    else if (m <= 3) s = Wl + (m - 1) * 16384;
    else if (m <= 6) s = Wr + (m - 4) * 16384;
    else s = Wc1;
    v = s[k * 128 + n];
  } else {
    int rem = idx - NMAIN;
    int n = rem >> 7, k = rem & 127;
    v = (n < OUTD) ? Wc2[k * OUTD + n] : 0.f;
  }
  wt[idx] = f2bf(v);
}

// ---------- aggregation: 4 column passes, quarter-wave per row-slice ----------
// Pass p gathers the 64B slice (cols p*32..p*32+31) of each neighbor row from
// the blocked h layout; slice working set 3.2MB fits per-XCD L2. One dispatch:
// 8192 blocks, pass = bid>>11; 2048 blocks co-resident => passes run roughly
// sequentially. csr indices for the next batch prefetched while data in flight.
__global__ __launch_bounds__(256) void k_agg(const unsigned short* __restrict__ h,
                                             const int* __restrict__ csr,
                                             const int* __restrict__ offs,
                                             const float* __restrict__ dinv,
                                             unsigned short* __restrict__ agg) {
  const int lane = threadIdx.x & 63;
  const int c = lane & 15;       // uint column within 64B slice
  const int q = lane >> 4;       // quarter 0..3: which row of the 4-row group
  const int pass = blockIdx.x >> 11;        // 0..3
  const int bid = blockIdx.x & 2047;
  int gw = (bid * 256 + (int)threadIdx.x) >> 6;   // wave id within pass
  const int nw = 2048 * 4;                        // waves per pass
  const unsigned* hs = (const unsigned*)(h + (size_t)pass * (NN * 32)); // row stride 16 uints
  unsigned* ag32 = (unsigned*)agg;
  for (int n = gw; n < NN; n += nw) {
    const int s = offs[n], e = offs[n + 1];
    float f0=0,f1=0,f2=0,f3=0,f4=0,f5=0,f6=0,f7=0;
    int k = s;
    int i0, i1, i2, i3;
    bool have = (k + 16 <= e);
    if (have) { i0=csr[k+q]; i1=csr[k+4+q]; i2=csr[k+8+q]; i3=csr[k+12+q]; }
    while (have) {
      unsigned u0 = hs[i0*16+c], u1 = hs[i1*16+c], u2 = hs[i2*16+c], u3 = hs[i3*16+c];
      k += 16;
      have = (k + 16 <= e);
      if (have) { i0=csr[k+q]; i1=csr[k+4+q]; i2=csr[k+8+q]; i3=csr[k+12+q]; }
      f0 += bflo(u0); f1 += bfhi(u0);
      f2 += bflo(u1); f3 += bfhi(u1);
      f4 += bflo(u2); f5 += bfhi(u2);
      f6 += bflo(u3); f7 += bfhi(u3);
    }
    for (; k < e; k += 4) {
      if (k + q < e) {
        unsigned u = hs[csr[k + q] * 16 + c];
        f0 += bflo(u); f1 += bfhi(u);
      }
    }
    float slo = (f0 + f2) + (f4 + f6), shi = (f1 + f3) + (f5 + f7);
    slo += __shfl_xor(slo, 16); shi += __shfl_xor(shi, 16);
    slo += __shfl_xor(slo, 32); shi += __shfl_xor(shi, 32);
    if (q == 0) {
      float di = dinv[n];
      // agg stays ROW-major: uint index n*64 + pass*16 + c
      ag32[n * 64 + pass * 16 + c] = pack2(slo * di, shi * di);
    }
  }
}

// ---------- GEMM: h0 = x @ W_in + b_in (x fp32, out bf16 blocked) ----------
__global__ __launch_bounds__(256) void k_lin_in(const float* __restrict__ x,
                                                const unsigned short* __restrict__ Wt,
                                                const float* __restrict__ bias,
                                                unsigned short* __restrict__ hout) {
  const int lane = threadIdx.x & 63, w = threadIdx.x >> 6;
  const int wr = w >> 1, wc = w & 1;
  const int r15 = lane & 15, khi = lane >> 4;
  const int mbase = blockIdx.x * 128 + wr * 64, nbase = wc * 64;
  f32x4 acc[4][4] = {};
#pragma unroll
  for (int ks = 0; ks < 4; ++ks) {
    const int kk = ks * 32 + khi * 8;
    bf16x8 af[4], bq[4];
#pragma unroll
    for (int i = 0; i < 4; i++) {
      int row = mbase + i * 16 + r15; row = row < NN ? row : NN - 1;
      const f32x4* p = (const f32x4*)(x + row * HID + kk);
      f32x4 lo = p[0], hi = p[1];
      i32x4 t;
      t[0] = pack2(lo[0], lo[1]); t[1] = pack2(lo[2], lo[3]);
      t[2] = pack2(hi[0], hi[1]); t[3] = pack2(hi[2], hi[3]);
      af[i] = __builtin_bit_cast(bf16x8, t);
    }
#pragma unroll
    for (int j = 0; j < 4; j++) {
      int col = nbase + j * 16 + r15;
      bq[j] = *(const bf16x8*)(Wt + col * HID + kk);
    }
#pragma unroll
    for (int i = 0; i < 4; i++)
#pragma unroll
      for (int j = 0; j < 4; j++) acc[i][j] = mfma(af[i], bq[j], acc[i][j]);
  }
  float b4[4];
#pragma unroll
  for (int j = 0; j < 4; j++) b4[j] = bias[nbase + j * 16 + r15];
#pragma unroll
  for (int i = 0; i < 4; i++) {
    const int rb = mbase + i * 16 + khi * 4;
#pragma unroll
    for (int e = 0; e < 4; e++) {
      const int r = rb + e;
      if (r < NN) {
#pragma unroll
        for (int j = 0; j < 4; j++)
          hout[haddr(r, nbase + j * 16 + r15)] = f2bf(acc[i][j][e] + b4[j]);
      }
    }
  }
}

// ---------- GEMM: h_new = relu(h @ Wl + agg @ Wr + bl) ----------
// hp/hout blocked layout; ag row-major.
__global__ __launch_bounds__(256) void k_layer(const unsigned short* __restrict__ hp,
                                               const unsigned short* __restrict__ ag,
                                               const unsigned short* __restrict__ WtL,
                                               const unsigned short* __restrict__ WtR,
                                               const float* __restrict__ bias,
                                               unsigned short* __restrict__ hout) {
  const int lane = threadIdx.x & 63, w = threadIdx.x >> 6;
  const int wr = w >> 1, wc = w & 1;
  const int r15 = lane & 15, khi = lane >> 4;
  const int mbase = blockIdx.x * 128 + wr * 64, nbase = wc * 64;
  f32x4 acc[4][4] = {};
#pragma unroll
  for (int ph = 0; ph < 2; ++ph) {
    const unsigned short* A = ph ? ag : hp;
    const unsigned short* B = ph ? WtR : WtL;
#pragma unroll
    for (int ks = 0; ks < 4; ++ks) {
      const int kk = ks * 32 + khi * 8;
      bf16x8 af[4], bq[4];
#pragma unroll
      for (int i = 0; i < 4; i++) {
        int row = mbase + i * 16 + r15; row = row < NN ? row : NN - 1;
        af[i] = *(const bf16x8*)(A + (ph ? (row * HID + kk) : haddr(row, kk)));
      }
#pragma unroll
      for (int j = 0; j < 4; j++) {
        int col = nbase + j * 16 + r15;
        bq[j] = *(const bf16x8*)(B + col * HID + kk);
      }
#pragma unroll
      for (int i = 0; i < 4; i++)
#pragma unroll
        for (int j = 0; j < 4; j++) acc[i][j] = mfma(af[i], bq[j], acc[i][j]);
    }
  }
  float b4[4];
#pragma unroll
  for (int j = 0; j < 4; j++) b4[j] = bias[nbase + j * 16 + r15];
#pragma unroll
  for (int i = 0; i < 4; i++) {
    const int rb = mbase + i * 16 + khi * 4;
#pragma unroll
    for (int e = 0; e < 4; e++) {
      const int r = rb + e;
      if (r < NN) {
#pragma unroll
        for (int j = 0; j < 4; j++) {
          float v = acc[i][j][e] + b4[j];
          v = fmaxf(v, 0.f);
          hout[haddr(r, nbase + j * 16 + r15)] = f2bf(v);
        }
      }
    }
  }
}

// ---------- classifier: out = relu((h1+h2+h3)@Wc1+bc1)@Wc2+bc2 ----------
// h1..h3 blocked layout.
__global__ __launch_bounds__(256) void k_cls(const unsigned short* __restrict__ h1,
                                             const unsigned short* __restrict__ h2,
                                             const unsigned short* __restrict__ h3,
                                             const unsigned short* __restrict__ WtC1,
                                             const float* __restrict__ bc1,
                                             const unsigned short* __restrict__ WtC2,
                                             const float* __restrict__ bc2,
                                             float* __restrict__ out) {
  __shared__ unsigned short hc[128 * 136];  // padded row stride 136
  const int lane = threadIdx.x & 63, w = threadIdx.x >> 6;
  const int wr = w >> 1, wc = w & 1;
  const int r15 = lane & 15, khi = lane >> 4;
  const int mbase = blockIdx.x * 128 + wr * 64, nbase = wc * 64;
  // stage 1: hc = relu((h1+h2+h3) @ Wc1 + bc1)
  {
    f32x4 acc[4][4] = {};
#pragma unroll
    for (int ks = 0; ks < 4; ++ks) {
      const int kk = ks * 32 + khi * 8;
      bf16x8 af[4], bq[4];
#pragma unroll
      for (int i = 0; i < 4; i++) {
        int row = mbase + i * 16 + r15; row = row < NN ? row : NN - 1;
        const int ha = haddr(row, kk);
        i32x4 u = *(const i32x4*)(h1 + ha);
        i32x4 v = *(const i32x4*)(h2 + ha);
        i32x4 q = *(const i32x4*)(h3 + ha);
        i32x4 t;
#pragma unroll
        for (int cc = 0; cc < 4; cc++) {
          unsigned uu = u[cc], vv = v[cc], qq = q[cc];
          t[cc] = pack2(bflo(uu) + bflo(vv) + bflo(qq), bfhi(uu) + bfhi(vv) + bfhi(qq));
        }
        af[i] = __builtin_bit_cast(bf16x8, t);
      }
#pragma unroll
      for (int j = 0; j < 4; j++) {
        int col = nbase + j * 16 + r15;
        bq[j] = *(const bf16x8*)(WtC1 + col * HID + kk);
      }
#pragma unroll
      for (int i = 0; i < 4; i++)
#pragma unroll
        for (int j = 0; j < 4; j++) acc[i][j] = mfma(af[i], bq[j], acc[i][j]);
    }
    float b4[4];
#pragma unroll
    for (int j = 0; j < 4; j++) b4[j] = bc1[nbase + j * 16 + r15];
#pragma unroll
    for (int i = 0; i < 4; i++) {
      const int rT = wr * 64 + i * 16 + khi * 4;
#pragma unroll
      for (int e = 0; e < 4; e++) {
#pragma unroll
        for (int j = 0; j < 4; j++) {
          float v = fmaxf(acc[i][j][e] + b4[j], 0.f);
          hc[(rT + e) * 136 + nbase + j * 16 + r15] = f2bf(v);
        }
      }
    }
  }
  __syncthreads();
  // stage 2: out = hc @ Wc2 + bc2
  {
    f32x4 a2[2][3] = {};
#pragma unroll
    for (int ks = 0; ks < 4; ++ks) {
      const int kk = ks * 32 + khi * 8;
      bf16x8 af[2], bq[3];
#pragma unroll
      for (int i = 0; i < 2; i++) {
        int rT = w * 32 + i * 16 + r15;
        af[i] = *(const bf16x8*)&hc[rT * 136 + kk];
      }
#pragma unroll
      for (int j = 0; j < 3; j++) {
        int col = j * 16 + r15;
        bq[j] = *(const bf16x8*)(WtC2 + col * HID + kk);
      }
#pragma unroll
      for (int i = 0; i < 2; i++)
#pragma unroll
        for (int j = 0; j < 3; j++) a2[i][j] = mfma(af[i], bq[j], a2[i][j]);
    }
#pragma unroll
    for (int j = 0; j < 3; j++) {
      const int col = j * 16 + r15;
      const float b = (col < OUTD) ? bc2[col] : 0.f;
#pragma unroll
      for (int i = 0; i < 2; i++) {
        const int rT = w * 32 + i * 16 + khi * 4;
#pragma unroll
        for (int e = 0; e < 4; e++) {
          const int gr = blockIdx.x * 128 + rT + e;
          if (gr < NN && col < OUTD) out[gr * OUTD + col] = a2[i][j][e] + b;
        }
      }
    }
  }
}

// ---------- launch ----------
extern "C" void kernel_launch(void* const* d_in, const int* in_sizes, int n_in,
                              void* d_out, int out_size, void* d_ws, size_t ws_size,
                              hipStream_t stream) {
  (void)in_sizes; (void)n_in; (void)out_size; (void)ws_size;
  const float* x   = (const float*)d_in[0];
  const int*   ei  = (const int*)d_in[1];
  const float* Win = (const float*)d_in[2];
  const float* bin = (const float*)d_in[3];
  const float* Wl  = (const float*)d_in[4];
  const float* Wr  = (const float*)d_in[5];
  const float* bl  = (const float*)d_in[6];
  const float* Wc1 = (const float*)d_in[7];
  const float* bc1 = (const float*)d_in[8];
  const float* Wc2 = (const float*)d_in[9];
  const float* bc2 = (const float*)d_in[10];
  float* out = (float*)d_out;

  char* ws = (char*)d_ws;
  size_t off = 0;
  auto take = [&](size_t bytes) -> char* {
    char* p = ws + off; off = (off + bytes + 255) & ~(size_t)255; return p;
  };
  int* deg        = (int*)take((size_t)NN * 4);
  int* offs       = (int*)take((size_t)(NN + 1) * 4);
  int* pos        = (int*)take((size_t)NE * 4);
  int* bsum       = (int*)take(256 * 4);
  float* dinv     = (float*)take((size_t)NN * 4);
  int* csr        = (int*)take((size_t)NE * 4);
  unsigned short* wt  = (unsigned short*)take((size_t)(8 * 16384 + 48 * 128) * 2);
  unsigned short* h0  = (unsigned short*)take((size_t)NN * HID * 2);
  unsigned short* h1  = (unsigned short*)take((size_t)NN * HID * 2);
  unsigned short* h2  = (unsigned short*)take((size_t)NN * HID * 2);
  unsigned short* h3  = (unsigned short*)take((size_t)NN * HID * 2);
  unsigned short* agg = (unsigned short*)take((size_t)NN * HID * 2);

  const int* esrc = ei;
  const int* edst = ei + NE;

  k_prep<<<(8 * 16384 + 48 * 128 + 255) / 256, 256, 0, stream>>>(Win, Wl, Wr, Wc1, Wc2, wt, deg);
  k_deg<<<(NE + 255) / 256, 256, 0, stream>>>(edst, deg, pos);
  k_blocksum<<<NBLK, 256, 0, stream>>>(deg, bsum);
  k_scan3<<<NBLK, 256, 0, stream>>>(deg, bsum, offs, dinv);
  k_fill<<<(NE + 255) / 256, 256, 0, stream>>>(esrc, edst, pos, offs, csr);
  k_lin_in<<<(NN + 127) / 128, 256, 0, stream>>>(x, wt, bin, h0);

  unsigned short* hs[4] = {h0, h1, h2, h3};
  for (int i = 0; i < 3; i++) {
    k_agg<<<8192, 256, 0, stream>>>(hs[i], csr, offs, dinv, agg);
    k_layer<<<(NN + 127) / 128, 256, 0, stream>>>(hs[i], agg, wt + (1 + i) * 16384,
                                                  wt + (4 + i) * 16384, bl + i * HID, hs[i + 1]);
  }
  k_cls<<<(NN + 127) / 128, 256, 0, stream>>>(h1, h2, h3, wt + 7 * 16384, bc1,
                                              wt + 8 * 16384, bc2, out);
}

// Round 9
// 358.265 us; speedup vs baseline: 1.1615x; 1.0503x over previous
//
#include <hip/hip_runtime.h>

#define NN   50000
#define NE   800000
#define HID  128
#define OUTD 40
#define NBLK 196  // ceil(NN/256)

typedef float f32x4  __attribute__((ext_vector_type(4)));
typedef int   i32x4  __attribute__((ext_vector_type(4)));
typedef short bf16x8 __attribute__((ext_vector_type(8)));

// ---------- helpers ----------
__device__ __forceinline__ f32x4 mfma(bf16x8 a, bf16x8 b, f32x4 c) {
  return __builtin_amdgcn_mfma_f32_16x16x32_bf16(a, b, c, 0, 0, 0);
}
__device__ __forceinline__ unsigned short f2bf(float f) {
  unsigned u = __builtin_bit_cast(unsigned, f);
  u += 0x7fffu + ((u >> 16) & 1u);
  return (unsigned short)(u >> 16);
}
__device__ __forceinline__ unsigned pack2(float lo, float hi) {
  return (unsigned)f2bf(lo) | ((unsigned)f2bf(hi) << 16);
}
__device__ __forceinline__ float bflo(unsigned v){ return __builtin_bit_cast(float, v << 16); }
__device__ __forceinline__ float bfhi(unsigned v){ return __builtin_bit_cast(float, v & 0xffff0000u); }

// h buffers are column-blocked: 4 blocks of 32 cols; a 32-col slice of all
// nodes = 3.2MB, fits each XCD's 4MiB L2 as a private copy during a pass.
// bf16 index of (row, col):
__device__ __forceinline__ int haddr(int row, int col) {
  return (col >> 5) * (NN * 32) + row * 32 + (col & 31);
}

// ---------- CSR build ----------
__global__ void k_deg(const int* __restrict__ dst, int* __restrict__ deg,
                      int* __restrict__ pos) {
  int i = blockIdx.x * blockDim.x + threadIdx.x;
  if (i < NE) pos[i] = atomicAdd(&deg[dst[i]], 1);
}

__global__ void k_blocksum(const int* __restrict__ deg, int* __restrict__ bsum) {
  __shared__ int s[256];
  int t = threadIdx.x, i = blockIdx.x * 256 + t;
  s[t] = (i < NN) ? deg[i] : 0;
  __syncthreads();
  for (int o = 128; o > 0; o >>= 1) { if (t < o) s[t] += s[t + o]; __syncthreads(); }
  if (t == 0) bsum[blockIdx.x] = s[0];
}

// fused: per-block exclusive base (reduce bsum[0..blockIdx)) + local scan
__global__ void k_scan3(const int* __restrict__ deg, const int* __restrict__ bsum,
                        int* __restrict__ offs, float* __restrict__ dinv) {
  __shared__ int sb[256];
  __shared__ int s[256];
  int t = threadIdx.x, i = blockIdx.x * 256 + t;
  sb[t] = (t < NBLK && t < blockIdx.x) ? bsum[t] : 0;
  int v = (i < NN) ? deg[i] : 0;
  s[t] = v;
  __syncthreads();
  for (int o = 128; o > 0; o >>= 1) { if (t < o) sb[t] += sb[t + o]; __syncthreads(); }
  for (int o = 1; o < 256; o <<= 1) {
    int x = (t >= o) ? s[t - o] : 0;
    __syncthreads(); s[t] += x; __syncthreads();
  }
  int off = sb[0] + s[t] - v;  // exclusive within-array offset
  if (i < NN) {
    offs[i] = off;
    dinv[i] = 1.0f / (float)(v > 0 ? v : 1);
  }
  if (i == 0) offs[NN] = NE;
}

// no atomics: position precomputed in k_deg
__global__ void k_fill(const int* __restrict__ src, const int* __restrict__ dst,
                       const int* __restrict__ pos, const int* __restrict__ offs,
                       int* __restrict__ csr) {
  int i = blockIdx.x * blockDim.x + threadIdx.x;
  if (i < NE) {
    csr[offs[dst[i]] + pos[i]] = src[i];
  }
}

// ---------- weight prep: transpose + bf16 cast into ws; also zeros deg ----------
// wt layout: m=0 WtIn, m=1..3 WtL[i], m=4..6 WtR[i], m=7 WtC1, then WtC2 [48][128]
__global__ void k_prep(const float* __restrict__ Win, const float* __restrict__ Wl,
                       const float* __restrict__ Wr, const float* __restrict__ Wc1,
                       const float* __restrict__ Wc2, unsigned short* __restrict__ wt,
                       int* __restrict__ deg) {
  int idx = blockIdx.x * 256 + threadIdx.x;
  if (idx < NN) deg[idx] = 0;  // folded memset
  const int NMAIN = 8 * 16384;
  if (idx >= NMAIN + 48 * 128) return;
  float v;
  if (idx < NMAIN) {
    int m = idx >> 14, rem = idx & 16383;
    int n = rem >> 7, k = rem & 127;
    const float* s;
    if (m == 0) s = Win;
    else if (m <= 3) s = Wl + (m - 1) * 16384;
    else if (m <= 6) s = Wr + (m - 4) * 16384;
    else s = Wc1;
    v = s[k * 128 + n];
  } else {
    int rem = idx - NMAIN;
    int n = rem >> 7, k = rem & 127;
    v = (n < OUTD) ? Wc2[k * OUTD + n] : 0.f;
  }
  wt[idx] = f2bf(v);
}

// ---------- aggregation: ONE column slice per dispatch ----------
// Slice = 32 cols (64B/row). 8 lanes x uint2 = one row; one wave-instruction
// covers 8 rows (512B). 2-batch unroll + index prefetch. Working set 3.2MB
// fits per-XCD L2, so gathers are ~200cy L2 hits instead of ~600cy L3.
__global__ __launch_bounds__(256) void k_agg_pass(const unsigned short* __restrict__ h,
                                                  const int* __restrict__ csr,
                                                  const int* __restrict__ offs,
                                                  const float* __restrict__ dinv,
                                                  unsigned short* __restrict__ agg,
                                                  int pass) {
  const int lane = threadIdx.x & 63;
  const int c = lane & 7;    // uint2 index within 64B slice
  const int o = lane >> 3;   // row within 8-row group
  int gw = (blockIdx.x * 256 + (int)threadIdx.x) >> 6;
  const int nw = (gridDim.x * 256) >> 6;
  const uint2* hs = (const uint2*)(h + (size_t)pass * (NN * 32));  // row stride 8 uint2
  uint2* ag2 = (uint2*)agg;  // row-major, 32 uint2 per row
  for (int n = gw; n < NN; n += nw) {
    const int s = offs[n], e = offs[n + 1];
    float a0=0,a1=0,a2=0,a3=0, b0=0,b1=0,b2=0,b3=0;
    int k = s;
    int ia = 0, ib = 0;
    bool have2 = (k + 16 <= e);
    if (have2) { ia = csr[k + o]; ib = csr[k + 8 + o]; }
    while (have2) {
      uint2 va = hs[ia * 8 + c];
      uint2 vb = hs[ib * 8 + c];
      k += 16;
      have2 = (k + 16 <= e);
      if (have2) { ia = csr[k + o]; ib = csr[k + 8 + o]; }  // prefetch
      a0 += bflo(va.x); a1 += bfhi(va.x); a2 += bflo(va.y); a3 += bfhi(va.y);
      b0 += bflo(vb.x); b1 += bfhi(vb.x); b2 += bflo(vb.y); b3 += bfhi(vb.y);
    }
    if (k + 8 <= e) {
      int i = csr[k + o];
      uint2 v = hs[i * 8 + c];
      a0 += bflo(v.x); a1 += bfhi(v.x); a2 += bflo(v.y); a3 += bfhi(v.y);
      k += 8;
    }
    if (k < e && k + o < e) {  // remainder <8 rows, predicated per octant
      int i = csr[k + o];
      uint2 v = hs[i * 8 + c];
      b0 += bflo(v.x); b1 += bfhi(v.x); b2 += bflo(v.y); b3 += bfhi(v.y);
    }
    float f0 = a0 + b0, f1 = a1 + b1, f2 = a2 + b2, f3 = a3 + b3;
    f0 += __shfl_xor(f0, 8);  f1 += __shfl_xor(f1, 8);
    f2 += __shfl_xor(f2, 8);  f3 += __shfl_xor(f3, 8);
    f0 += __shfl_xor(f0, 16); f1 += __shfl_xor(f1, 16);
    f2 += __shfl_xor(f2, 16); f3 += __shfl_xor(f3, 16);
    f0 += __shfl_xor(f0, 32); f1 += __shfl_xor(f1, 32);
    f2 += __shfl_xor(f2, 32); f3 += __shfl_xor(f3, 32);
    if (o == 0) {
      float di = dinv[n];
      uint2 w;
      w.x = pack2(f0 * di, f1 * di);
      w.y = pack2(f2 * di, f3 * di);
      ag2[n * 32 + pass * 8 + c] = w;
    }
  }
}

// ---------- GEMM: h0 = x @ W_in + b_in (x fp32, out bf16 blocked) ----------
__global__ __launch_bounds__(256) void k_lin_in(const float* __restrict__ x,
                                                const unsigned short* __restrict__ Wt,
                                                const float* __restrict__ bias,
                                                unsigned short* __restrict__ hout) {
  const int lane = threadIdx.x & 63, w = threadIdx.x >> 6;
  const int wr = w >> 1, wc = w & 1;
  const int r15 = lane & 15, khi = lane >> 4;
  const int mbase = blockIdx.x * 128 + wr * 64, nbase = wc * 64;
  f32x4 acc[4][4] = {};
#pragma unroll
  for (int ks = 0; ks < 4; ++ks) {
    const int kk = ks * 32 + khi * 8;
    bf16x8 af[4], bq[4];
#pragma unroll
    for (int i = 0; i < 4; i++) {
      int row = mbase + i * 16 + r15; row = row < NN ? row : NN - 1;
      const f32x4* p = (const f32x4*)(x + row * HID + kk);
      f32x4 lo = p[0], hi = p[1];
      i32x4 t;
      t[0] = pack2(lo[0], lo[1]); t[1] = pack2(lo[2], lo[3]);
      t[2] = pack2(hi[0], hi[1]); t[3] = pack2(hi[2], hi[3]);
      af[i] = __builtin_bit_cast(bf16x8, t);
    }
#pragma unroll
    for (int j = 0; j < 4; j++) {
      int col = nbase + j * 16 + r15;
      bq[j] = *(const bf16x8*)(Wt + col * HID + kk);
    }
#pragma unroll
    for (int i = 0; i < 4; i++)
#pragma unroll
      for (int j = 0; j < 4; j++) acc[i][j] = mfma(af[i], bq[j], acc[i][j]);
  }
  float b4[4];
#pragma unroll
  for (int j = 0; j < 4; j++) b4[j] = bias[nbase + j * 16 + r15];
#pragma unroll
  for (int i = 0; i < 4; i++) {
    const int rb = mbase + i * 16 + khi * 4;
#pragma unroll
    for (int e = 0; e < 4; e++) {
      const int r = rb + e;
      if (r < NN) {
#pragma unroll
        for (int j = 0; j < 4; j++)
          hout[haddr(r, nbase + j * 16 + r15)] = f2bf(acc[i][j][e] + b4[j]);
      }
    }
  }
}

// ---------- GEMM: h_new = relu(h @ Wl + agg @ Wr + bl) ----------
// hp/hout blocked layout; ag row-major.
__global__ __launch_bounds__(256) void k_layer(const unsigned short* __restrict__ hp,
                                               const unsigned short* __restrict__ ag,
                                               const unsigned short* __restrict__ WtL,
                                               const unsigned short* __restrict__ WtR,
                                               const float* __restrict__ bias,
                                               unsigned short* __restrict__ hout) {
  const int lane = threadIdx.x & 63, w = threadIdx.x >> 6;
  const int wr = w >> 1, wc = w & 1;
  const int r15 = lane & 15, khi = lane >> 4;
  const int mbase = blockIdx.x * 128 + wr * 64, nbase = wc * 64;
  f32x4 acc[4][4] = {};
#pragma unroll
  for (int ph = 0; ph < 2; ++ph) {
    const unsigned short* A = ph ? ag : hp;
    const unsigned short* B = ph ? WtR : WtL;
#pragma unroll
    for (int ks = 0; ks < 4; ++ks) {
      const int kk = ks * 32 + khi * 8;
      bf16x8 af[4], bq[4];
#pragma unroll
      for (int i = 0; i < 4; i++) {
        int row = mbase + i * 16 + r15; row = row < NN ? row : NN - 1;
        af[i] = *(const bf16x8*)(A + (ph ? (row * HID + kk) : haddr(row, kk)));
      }
#pragma unroll
      for (int j = 0; j < 4; j++) {
        int col = nbase + j * 16 + r15;
        bq[j] = *(const bf16x8*)(B + col * HID + kk);
      }
#pragma unroll
      for (int i = 0; i < 4; i++)
#pragma unroll
        for (int j = 0; j < 4; j++) acc[i][j] = mfma(af[i], bq[j], acc[i][j]);
    }
  }
  float b4[4];
#pragma unroll
  for (int j = 0; j < 4; j++) b4[j] = bias[nbase + j * 16 + r15];
#pragma unroll
  for (int i = 0; i < 4; i++) {
    const int rb = mbase + i * 16 + khi * 4;
#pragma unroll
    for (int e = 0; e < 4; e++) {
      const int r = rb + e;
      if (r < NN) {
#pragma unroll
        for (int j = 0; j < 4; j++) {
          float v = acc[i][j][e] + b4[j];
          v = fmaxf(v, 0.f);
          hout[haddr(r, nbase + j * 16 + r15)] = f2bf(v);
        }
      }
    }
  }
}

// ---------- classifier: out = relu((h1+h2+h3)@Wc1+bc1)@Wc2+bc2 ----------
// h1..h3 blocked layout.
__global__ __launch_bounds__(256) void k_cls(const unsigned short* __restrict__ h1,
                                             const unsigned short* __restrict__ h2,
                                             const unsigned short* __restrict__ h3,
                                             const unsigned short* __restrict__ WtC1,
                                             const float* __restrict__ bc1,
                                             const unsigned short* __restrict__ WtC2,
                                             const float* __restrict__ bc2,
                                             float* __restrict__ out) {
  __shared__ unsigned short hc[128 * 136];  // padded row stride 136
  const int lane = threadIdx.x & 63, w = threadIdx.x >> 6;
  const int wr = w >> 1, wc = w & 1;
  const int r15 = lane & 15, khi = lane >> 4;
  const int mbase = blockIdx.x * 128 + wr * 64, nbase = wc * 64;
  // stage 1: hc = relu((h1+h2+h3) @ Wc1 + bc1)
  {
    f32x4 acc[4][4] = {};
#pragma unroll
    for (int ks = 0; ks < 4; ++ks) {
      const int kk = ks * 32 + khi * 8;
      bf16x8 af[4], bq[4];
#pragma unroll
      for (int i = 0; i < 4; i++) {
        int row = mbase + i * 16 + r15; row = row < NN ? row : NN - 1;
        const int ha = haddr(row, kk);
        i32x4 u = *(const i32x4*)(h1 + ha);
        i32x4 v = *(const i32x4*)(h2 + ha);
        i32x4 q = *(const i32x4*)(h3 + ha);
        i32x4 t;
#pragma unroll
        for (int cc = 0; cc < 4; cc++) {
          unsigned uu = u[cc], vv = v[cc], qq = q[cc];
          t[cc] = pack2(bflo(uu) + bflo(vv) + bflo(qq), bfhi(uu) + bfhi(vv) + bfhi(qq));
        }
        af[i] = __builtin_bit_cast(bf16x8, t);
      }
#pragma unroll
      for (int j = 0; j < 4; j++) {
        int col = nbase + j * 16 + r15;
        bq[j] = *(const bf16x8*)(WtC1 + col * HID + kk);
      }
#pragma unroll
      for (int i = 0; i < 4; i++)
#pragma unroll
        for (int j = 0; j < 4; j++) acc[i][j] = mfma(af[i], bq[j], acc[i][j]);
    }
    float b4[4];
#pragma unroll
    for (int j = 0; j < 4; j++) b4[j] = bc1[nbase + j * 16 + r15];
#pragma unroll
    for (int i = 0; i < 4; i++) {
      const int rT = wr * 64 + i * 16 + khi * 4;
#pragma unroll
      for (int e = 0; e < 4; e++) {
#pragma unroll
        for (int j = 0; j < 4; j++) {
          float v = fmaxf(acc[i][j][e] + b4[j], 0.f);
          hc[(rT + e) * 136 + nbase + j * 16 + r15] = f2bf(v);
        }
      }
    }
  }
  __syncthreads();
  // stage 2: out = hc @ Wc2 + bc2
  {
    f32x4 a2[2][3] = {};
#pragma unroll
    for (int ks = 0; ks < 4; ++ks) {
      const int kk = ks * 32 + khi * 8;
      bf16x8 af[2], bq[3];
#pragma unroll
      for (int i = 0; i < 2; i++) {
        int rT = w * 32 + i * 16 + r15;
        af[i] = *(const bf16x8*)&hc[rT * 136 + kk];
      }
#pragma unroll
      for (int j = 0; j < 3; j++) {
        int col = j * 16 + r15;
        bq[j] = *(const bf16x8*)(WtC2 + col * HID + kk);
      }
#pragma unroll
      for (int i = 0; i < 2; i++)
#pragma unroll
        for (int j = 0; j < 3; j++) a2[i][j] = mfma(af[i], bq[j], a2[i][j]);
    }
#pragma unroll
    for (int j = 0; j < 3; j++) {
      const int col = j * 16 + r15;
      const float b = (col < OUTD) ? bc2[col] : 0.f;
#pragma unroll
      for (int i = 0; i < 2; i++) {
        const int rT = w * 32 + i * 16 + khi * 4;
#pragma unroll
        for (int e = 0; e < 4; e++) {
          const int gr = blockIdx.x * 128 + rT + e;
          if (gr < NN && col < OUTD) out[gr * OUTD + col] = a2[i][j][e] + b;
        }
      }
    }
  }
}

// ---------- launch ----------
extern "C" void kernel_launch(void* const* d_in, const int* in_sizes, int n_in,
                              void* d_out, int out_size, void* d_ws, size_t ws_size,
                              hipStream_t stream) {
  (void)in_sizes; (void)n_in; (void)out_size; (void)ws_size;
  const float* x   = (const float*)d_in[0];
  const int*   ei  = (const int*)d_in[1];
  const float* Win = (const float*)d_in[2];
  const float* bin = (const float*)d_in[3];
  const float* Wl  = (const float*)d_in[4];
  const float* Wr  = (const float*)d_in[5];
  const float* bl  = (const float*)d_in[6];
  const float* Wc1 = (const float*)d_in[7];
  const float* bc1 = (const float*)d_in[8];
  const float* Wc2 = (const float*)d_in[9];
  const float* bc2 = (const float*)d_in[10];
  float* out = (float*)d_out;

  char* ws = (char*)d_ws;
  size_t off = 0;
  auto take = [&](size_t bytes) -> char* {
    char* p = ws + off; off = (off + bytes + 255) & ~(size_t)255; return p;
  };
  int* deg        = (int*)take((size_t)NN * 4);
  int* offs       = (int*)take((size_t)(NN + 1) * 4);
  int* pos        = (int*)take((size_t)NE * 4);
  int* bsum       = (int*)take(256 * 4);
  float* dinv     = (float*)take((size_t)NN * 4);
  int* csr        = (int*)take((size_t)NE * 4);
  unsigned short* wt  = (unsigned short*)take((size_t)(8 * 16384 + 48 * 128) * 2);
  unsigned short* h0  = (unsigned short*)take((size_t)NN * HID * 2);
  unsigned short* h1  = (unsigned short*)take((size_t)NN * HID * 2);
  unsigned short* h2  = (unsigned short*)take((size_t)NN * HID * 2);
  unsigned short* h3  = (unsigned short*)take((size_t)NN * HID * 2);
  unsigned short* agg = (unsigned short*)take((size_t)NN * HID * 2);

  const int* esrc = ei;
  const int* edst = ei + NE;

  k_prep<<<(8 * 16384 + 48 * 128 + 255) / 256, 256, 0, stream>>>(Win, Wl, Wr, Wc1, Wc2, wt, deg);
  k_deg<<<(NE + 255) / 256, 256, 0, stream>>>(edst, deg, pos);
  k_blocksum<<<NBLK, 256, 0, stream>>>(deg, bsum);
  k_scan3<<<NBLK, 256, 0, stream>>>(deg, bsum, offs, dinv);
  k_fill<<<(NE + 255) / 256, 256, 0, stream>>>(esrc, edst, pos, offs, csr);
  k_lin_in<<<(NN + 127) / 128, 256, 0, stream>>>(x, wt, bin, h0);

  unsigned short* hs[4] = {h0, h1, h2, h3};
  for (int i = 0; i < 3; i++) {
    for (int p = 0; p < 4; p++)
      k_agg_pass<<<2048, 256, 0, stream>>>(hs[i], csr, offs, dinv, agg, p);
    k_layer<<<(NN + 127) / 128, 256, 0, stream>>>(hs[i], agg, wt + (1 + i) * 16384,
                                                  wt + (4 + i) * 16384, bl + i * HID, hs[i + 1]);
  }
  k_cls<<<(NN + 127) / 128, 256, 0, stream>>>(h1, h2, h3, wt + 7 * 16384, bc1,
                                              wt + 8 * 16384, bc2, out);
}

// Round 10
// 246.900 us; speedup vs baseline: 1.6854x; 1.4511x over previous
//
#include <hip/hip_runtime.h>

#define NN   50000
#define NE   800000
#define HID  128
#define OUTD 40
#define NBLK 196  // ceil(NN/256)

typedef float f32x4  __attribute__((ext_vector_type(4)));
typedef int   i32x4  __attribute__((ext_vector_type(4)));
typedef short bf16x8 __attribute__((ext_vector_type(8)));

// ---------- helpers ----------
__device__ __forceinline__ f32x4 mfma(bf16x8 a, bf16x8 b, f32x4 c) {
  return __builtin_amdgcn_mfma_f32_16x16x32_bf16(a, b, c, 0, 0, 0);
}
__device__ __forceinline__ unsigned short f2bf(float f) {
  unsigned u = __builtin_bit_cast(unsigned, f);
  u += 0x7fffu + ((u >> 16) & 1u);
  return (unsigned short)(u >> 16);
}
__device__ __forceinline__ unsigned pack2(float lo, float hi) {
  return (unsigned)f2bf(lo) | ((unsigned)f2bf(hi) << 16);
}
__device__ __forceinline__ float bflo(unsigned v){ return __builtin_bit_cast(float, v << 16); }
__device__ __forceinline__ float bfhi(unsigned v){ return __builtin_bit_cast(float, v & 0xffff0000u); }
__device__ __forceinline__ void acc8(float* a, uint4 v) {
  a[0] += bflo(v.x); a[1] += bfhi(v.x);
  a[2] += bflo(v.y); a[3] += bfhi(v.y);
  a[4] += bflo(v.z); a[5] += bfhi(v.z);
  a[6] += bflo(v.w); a[7] += bfhi(v.w);
}

// ---------- CSR build ----------
// k_deg: count in-degree AND record each edge's rank within its dst bucket.
__global__ void k_deg(const int* __restrict__ dst, int* __restrict__ deg,
                      int* __restrict__ pos) {
  int i = blockIdx.x * blockDim.x + threadIdx.x;
  if (i < NE) pos[i] = atomicAdd(&deg[dst[i]], 1);
}

__global__ void k_blocksum(const int* __restrict__ deg, int* __restrict__ bsum) {
  __shared__ int s[256];
  int t = threadIdx.x, i = blockIdx.x * 256 + t;
  s[t] = (i < NN) ? deg[i] : 0;
  __syncthreads();
  for (int o = 128; o > 0; o >>= 1) { if (t < o) s[t] += s[t + o]; __syncthreads(); }
  if (t == 0) bsum[blockIdx.x] = s[0];
}

// fused: per-block exclusive base (reduce bsum[0..blockIdx)) + local scan
__global__ void k_scan3(const int* __restrict__ deg, const int* __restrict__ bsum,
                        int* __restrict__ offs, float* __restrict__ dinv) {
  __shared__ int sb[256];
  __shared__ int s[256];
  int t = threadIdx.x, i = blockIdx.x * 256 + t;
  sb[t] = (t < NBLK && t < blockIdx.x) ? bsum[t] : 0;
  int v = (i < NN) ? deg[i] : 0;
  s[t] = v;
  __syncthreads();
  for (int o = 128; o > 0; o >>= 1) { if (t < o) sb[t] += sb[t + o]; __syncthreads(); }
  for (int o = 1; o < 256; o <<= 1) {
    int x = (t >= o) ? s[t - o] : 0;
    __syncthreads(); s[t] += x; __syncthreads();
  }
  int off = sb[0] + s[t] - v;  // exclusive within-array offset
  if (i < NN) {
    offs[i] = off;
    dinv[i] = 1.0f / (float)(v > 0 ? v : 1);
  }
  if (i == 0) offs[NN] = NE;
}

// no atomics: position precomputed in k_deg
__global__ void k_fill(const int* __restrict__ src, const int* __restrict__ dst,
                       const int* __restrict__ pos, const int* __restrict__ offs,
                       int* __restrict__ csr) {
  int i = blockIdx.x * blockDim.x + threadIdx.x;
  if (i < NE) {
    csr[offs[dst[i]] + pos[i]] = src[i];
  }
}

// ---------- weight prep: transpose + bf16 cast into ws; also zeros deg ----------
// wt layout: m=0 WtIn, m=1..3 WtL[i], m=4..6 WtR[i], m=7 WtC1, then WtC2 [48][128]
__global__ void k_prep(const float* __restrict__ Win, const float* __restrict__ Wl,
                       const float* __restrict__ Wr, const float* __restrict__ Wc1,
                       const float* __restrict__ Wc2, unsigned short* __restrict__ wt,
                       int* __restrict__ deg) {
  int idx = blockIdx.x * 256 + threadIdx.x;
  if (idx < NN) deg[idx] = 0;  // folded memset
  const int NMAIN = 8 * 16384;
  if (idx >= NMAIN + 48 * 128) return;
  float v;
  if (idx < NMAIN) {
    int m = idx >> 14, rem = idx & 16383;
    int n = rem >> 7, k = rem & 127;
    const float* s;
    if (m == 0) s = Win;
    else if (m <= 3) s = Wl + (m - 1) * 16384;
    else if (m <= 6) s = Wr + (m - 4) * 16384;
    else s = Wc1;
    v = s[k * 128 + n];
  } else {
    int rem = idx - NMAIN;
    int n = rem >> 7, k = rem & 127;
    v = (n < OUTD) ? Wc2[k * OUTD + n] : 0.f;
  }
  wt[idx] = f2bf(v);
}

// ---------- aggregation: quarter-wave uint4 (16 lanes x 16B = one 256B row),
// one VMEM instruction covers 4 rows (1KB); 8 rows/iter via 2 banks; csr
// indices for the next batch prefetched while data loads are in flight.
// 2 acc banks (16 VGPR) keeps total ~40 VGPR: the allocator keeps both
// uint4 gathers in flight (round-5's 4-bank version spilled that MLP).
__global__ __launch_bounds__(256) void k_agg(const unsigned short* __restrict__ h,
                                             const int* __restrict__ csr,
                                             const int* __restrict__ offs,
                                             const float* __restrict__ dinv,
                                             unsigned short* __restrict__ agg) {
  const int lane = threadIdx.x & 63;
  const int c = lane & 15;   // uint4 index within row (16 x 16B = 256B)
  const int q = lane >> 4;   // quarter 0..3: row within 4-row group
  int gw = (blockIdx.x * 256 + (int)threadIdx.x) >> 6;
  const int nw = (gridDim.x * 256) >> 6;
  const uint4* h4 = (const uint4*)h;  // row stride = 16 uint4
  uint4* ag4 = (uint4*)agg;
  for (int n = gw; n < NN; n += nw) {
    const int s = offs[n], e = offs[n + 1];
    float a[8] = {0, 0, 0, 0, 0, 0, 0, 0};
    float b[8] = {0, 0, 0, 0, 0, 0, 0, 0};
    int k = s;
    int ia = 0, ib = 0;
    bool have = (k + 8 <= e);
    if (have) { ia = csr[k + q]; ib = csr[k + 4 + q]; }
    while (have) {
      uint4 va = h4[ia * 16 + c];
      uint4 vb = h4[ib * 16 + c];
      k += 8;
      have = (k + 8 <= e);
      if (have) { ia = csr[k + q]; ib = csr[k + 4 + q]; }  // prefetch next batch
      acc8(a, va);
      acc8(b, vb);
    }
    for (; k < e; k += 4) {  // tail 1-7 rows, predicated per quarter
      if (k + q < e) {
        uint4 v = h4[csr[k + q] * 16 + c];
        acc8(a, v);
      }
    }
    float f0 = a[0] + b[0], f1 = a[1] + b[1], f2 = a[2] + b[2], f3 = a[3] + b[3];
    float f4 = a[4] + b[4], f5 = a[5] + b[5], f6 = a[6] + b[6], f7 = a[7] + b[7];
    f0 += __shfl_xor(f0, 16); f1 += __shfl_xor(f1, 16);
    f2 += __shfl_xor(f2, 16); f3 += __shfl_xor(f3, 16);
    f4 += __shfl_xor(f4, 16); f5 += __shfl_xor(f5, 16);
    f6 += __shfl_xor(f6, 16); f7 += __shfl_xor(f7, 16);
    f0 += __shfl_xor(f0, 32); f1 += __shfl_xor(f1, 32);
    f2 += __shfl_xor(f2, 32); f3 += __shfl_xor(f3, 32);
    f4 += __shfl_xor(f4, 32); f5 += __shfl_xor(f5, 32);
    f6 += __shfl_xor(f6, 32); f7 += __shfl_xor(f7, 32);
    if (q == 0) {
      float di = dinv[n];
      uint4 o;
      o.x = pack2(f0 * di, f1 * di);
      o.y = pack2(f2 * di, f3 * di);
      o.z = pack2(f4 * di, f5 * di);
      o.w = pack2(f6 * di, f7 * di);
      ag4[n * 16 + c] = o;
    }
  }
}

// ---------- GEMM: h0 = x @ W_in + b_in (x fp32, out bf16) ----------
__global__ __launch_bounds__(256) void k_lin_in(const float* __restrict__ x,
                                                const unsigned short* __restrict__ Wt,
                                                const float* __restrict__ bias,
                                                unsigned short* __restrict__ hout) {
  const int lane = threadIdx.x & 63, w = threadIdx.x >> 6;
  const int wr = w >> 1, wc = w & 1;
  const int r15 = lane & 15, khi = lane >> 4;
  const int mbase = blockIdx.x * 128 + wr * 64, nbase = wc * 64;
  f32x4 acc[4][4] = {};
#pragma unroll
  for (int ks = 0; ks < 4; ++ks) {
    const int kk = ks * 32 + khi * 8;
    bf16x8 af[4], bq[4];
#pragma unroll
    for (int i = 0; i < 4; i++) {
      int row = mbase + i * 16 + r15; row = row < NN ? row : NN - 1;
      const f32x4* p = (const f32x4*)(x + row * HID + kk);
      f32x4 lo = p[0], hi = p[1];
      i32x4 t;
      t[0] = pack2(lo[0], lo[1]); t[1] = pack2(lo[2], lo[3]);
      t[2] = pack2(hi[0], hi[1]); t[3] = pack2(hi[2], hi[3]);
      af[i] = __builtin_bit_cast(bf16x8, t);
    }
#pragma unroll
    for (int j = 0; j < 4; j++) {
      int col = nbase + j * 16 + r15;
      bq[j] = *(const bf16x8*)(Wt + col * HID + kk);
    }
#pragma unroll
    for (int i = 0; i < 4; i++)
#pragma unroll
      for (int j = 0; j < 4; j++) acc[i][j] = mfma(af[i], bq[j], acc[i][j]);
  }
  float b4[4];
#pragma unroll
  for (int j = 0; j < 4; j++) b4[j] = bias[nbase + j * 16 + r15];
#pragma unroll
  for (int i = 0; i < 4; i++) {
    const int rb = mbase + i * 16 + khi * 4;
#pragma unroll
    for (int e = 0; e < 4; e++) {
      const int r = rb + e;
      if (r < NN) {
#pragma unroll
        for (int j = 0; j < 4; j++)
          hout[r * HID + nbase + j * 16 + r15] = f2bf(acc[i][j][e] + b4[j]);
      }
    }
  }
}

// ---------- GEMM: h_new = relu(h @ Wl + agg @ Wr + bl) (bf16 in/out) ----------
__global__ __launch_bounds__(256) void k_layer(const unsigned short* __restrict__ hp,
                                               const unsigned short* __restrict__ ag,
                                               const unsigned short* __restrict__ WtL,
                                               const unsigned short* __restrict__ WtR,
                                               const float* __restrict__ bias,
                                               unsigned short* __restrict__ hout) {
  const int lane = threadIdx.x & 63, w = threadIdx.x >> 6;
  const int wr = w >> 1, wc = w & 1;
  const int r15 = lane & 15, khi = lane >> 4;
  const int mbase = blockIdx.x * 128 + wr * 64, nbase = wc * 64;
  f32x4 acc[4][4] = {};
#pragma unroll
  for (int ph = 0; ph < 2; ++ph) {
    const unsigned short* A = ph ? ag : hp;
    const unsigned short* B = ph ? WtR : WtL;
#pragma unroll
    for (int ks = 0; ks < 4; ++ks) {
      const int kk = ks * 32 + khi * 8;
      bf16x8 af[4], bq[4];
#pragma unroll
      for (int i = 0; i < 4; i++) {
        int row = mbase + i * 16 + r15; row = row < NN ? row : NN - 1;
        af[i] = *(const bf16x8*)(A + row * HID + kk);
      }
#pragma unroll
      for (int j = 0; j < 4; j++) {
        int col = nbase + j * 16 + r15;
        bq[j] = *(const bf16x8*)(B + col * HID + kk);
      }
#pragma unroll
      for (int i = 0; i < 4; i++)
#pragma unroll
        for (int j = 0; j < 4; j++) acc[i][j] = mfma(af[i], bq[j], acc[i][j]);
    }
  }
  float b4[4];
#pragma unroll
  for (int j = 0; j < 4; j++) b4[j] = bias[nbase + j * 16 + r15];
#pragma unroll
  for (int i = 0; i < 4; i++) {
    const int rb = mbase + i * 16 + khi * 4;
#pragma unroll
    for (int e = 0; e < 4; e++) {
      const int r = rb + e;
      if (r < NN) {
#pragma unroll
        for (int j = 0; j < 4; j++) {
          float v = acc[i][j][e] + b4[j];
          v = fmaxf(v, 0.f);
          hout[r * HID + nbase + j * 16 + r15] = f2bf(v);
        }
      }
    }
  }
}

// ---------- classifier: out = relu((h1+h2+h3)@Wc1+bc1)@Wc2+bc2 ----------
__global__ __launch_bounds__(256) void k_cls(const unsigned short* __restrict__ h1,
                                             const unsigned short* __restrict__ h2,
                                             const unsigned short* __restrict__ h3,
                                             const unsigned short* __restrict__ WtC1,
                                             const float* __restrict__ bc1,
                                             const unsigned short* __restrict__ WtC2,
                                             const float* __restrict__ bc2,
                                             float* __restrict__ out) {
  __shared__ unsigned short hc[128 * 136];  // padded row stride 136
  const int lane = threadIdx.x & 63, w = threadIdx.x >> 6;
  const int wr = w >> 1, wc = w & 1;
  const int r15 = lane & 15, khi = lane >> 4;
  const int mbase = blockIdx.x * 128 + wr * 64, nbase = wc * 64;
  // stage 1: hc = relu((h1+h2+h3) @ Wc1 + bc1)
  {
    f32x4 acc[4][4] = {};
#pragma unroll
    for (int ks = 0; ks < 4; ++ks) {
      const int kk = ks * 32 + khi * 8;
      bf16x8 af[4], bq[4];
#pragma unroll
      for (int i = 0; i < 4; i++) {
        int row = mbase + i * 16 + r15; row = row < NN ? row : NN - 1;
        i32x4 u = *(const i32x4*)(h1 + row * HID + kk);
        i32x4 v = *(const i32x4*)(h2 + row * HID + kk);
        i32x4 q = *(const i32x4*)(h3 + row * HID + kk);
        i32x4 t;
#pragma unroll
        for (int cc = 0; cc < 4; cc++) {
          unsigned uu = u[cc], vv = v[cc], qq = q[cc];
          t[cc] = pack2(bflo(uu) + bflo(vv) + bflo(qq), bfhi(uu) + bfhi(vv) + bfhi(qq));
        }
        af[i] = __builtin_bit_cast(bf16x8, t);
      }
#pragma unroll
      for (int j = 0; j < 4; j++) {
        int col = nbase + j * 16 + r15;
        bq[j] = *(const bf16x8*)(WtC1 + col * HID + kk);
      }
#pragma unroll
      for (int i = 0; i < 4; i++)
#pragma unroll
        for (int j = 0; j < 4; j++) acc[i][j] = mfma(af[i], bq[j], acc[i][j]);
    }
    float b4[4];
#pragma unroll
    for (int j = 0; j < 4; j++) b4[j] = bc1[nbase + j * 16 + r15];
#pragma unroll
    for (int i = 0; i < 4; i++) {
      const int rT = wr * 64 + i * 16 + khi * 4;
#pragma unroll
      for (int e = 0; e < 4; e++) {
#pragma unroll
        for (int j = 0; j < 4; j++) {
          float v = fmaxf(acc[i][j][e] + b4[j], 0.f);
          hc[(rT + e) * 136 + nbase + j * 16 + r15] = f2bf(v);
        }
      }
    }
  }
  __syncthreads();
  // stage 2: out = hc @ Wc2 + bc2
  {
    f32x4 a2[2][3] = {};
#pragma unroll
    for (int ks = 0; ks < 4; ++ks) {
      const int kk = ks * 32 + khi * 8;
      bf16x8 af[2], bq[3];
#pragma unroll
      for (int i = 0; i < 2; i++) {
        int rT = w * 32 + i * 16 + r15;
        af[i] = *(const bf16x8*)&hc[rT * 136 + kk];
      }
#pragma unroll
      for (int j = 0; j < 3; j++) {
        int col = j * 16 + r15;
        bq[j] = *(const bf16x8*)(WtC2 + col * HID + kk);
      }
#pragma unroll
      for (int i = 0; i < 2; i++)
#pragma unroll
        for (int j = 0; j < 3; j++) a2[i][j] = mfma(af[i], bq[j], a2[i][j]);
    }
#pragma unroll
    for (int j = 0; j < 3; j++) {
      const int col = j * 16 + r15;
      const float b = (col < OUTD) ? bc2[col] : 0.f;
#pragma unroll
      for (int i = 0; i < 2; i++) {
        const int rT = w * 32 + i * 16 + khi * 4;
#pragma unroll
        for (int e = 0; e < 4; e++) {
          const int gr = blockIdx.x * 128 + rT + e;
          if (gr < NN && col < OUTD) out[gr * OUTD + col] = a2[i][j][e] + b;
        }
      }
    }
  }
}

// ---------- launch ----------
extern "C" void kernel_launch(void* const* d_in, const int* in_sizes, int n_in,
                              void* d_out, int out_size, void* d_ws, size_t ws_size,
                              hipStream_t stream) {
  (void)in_sizes; (void)n_in; (void)out_size; (void)ws_size;
  const float* x   = (const float*)d_in[0];
  const int*   ei  = (const int*)d_in[1];
  const float* Win = (const float*)d_in[2];
  const float* bin = (const float*)d_in[3];
  const float* Wl  = (const float*)d_in[4];
  const float* Wr  = (const float*)d_in[5];
  const float* bl  = (const float*)d_in[6];
  const float* Wc1 = (const float*)d_in[7];
  const float* bc1 = (const float*)d_in[8];
  const float* Wc2 = (const float*)d_in[9];
  const float* bc2 = (const float*)d_in[10];
  float* out = (float*)d_out;

  char* ws = (char*)d_ws;
  size_t off = 0;
  auto take = [&](size_t bytes) -> char* {
    char* p = ws + off; off = (off + bytes + 255) & ~(size_t)255; return p;
  };
  int* deg        = (int*)take((size_t)NN * 4);
  int* offs       = (int*)take((size_t)(NN + 1) * 4);
  int* pos        = (int*)take((size_t)NE * 4);
  int* bsum       = (int*)take(256 * 4);
  float* dinv     = (float*)take((size_t)NN * 4);
  int* csr        = (int*)take((size_t)NE * 4);
  unsigned short* wt  = (unsigned short*)take((size_t)(8 * 16384 + 48 * 128) * 2);
  unsigned short* h0  = (unsigned short*)take((size_t)NN * HID * 2);
  unsigned short* h1  = (unsigned short*)take((size_t)NN * HID * 2);
  unsigned short* h2  = (unsigned short*)take((size_t)NN * HID * 2);
  unsigned short* h3  = (unsigned short*)take((size_t)NN * HID * 2);
  unsigned short* agg = (unsigned short*)take((size_t)NN * HID * 2);

  const int* esrc = ei;
  const int* edst = ei + NE;

  k_prep<<<(8 * 16384 + 48 * 128 + 255) / 256, 256, 0, stream>>>(Win, Wl, Wr, Wc1, Wc2, wt, deg);
  k_deg<<<(NE + 255) / 256, 256, 0, stream>>>(edst, deg, pos);
  k_blocksum<<<NBLK, 256, 0, stream>>>(deg, bsum);
  k_scan3<<<NBLK, 256, 0, stream>>>(deg, bsum, offs, dinv);
  k_fill<<<(NE + 255) / 256, 256, 0, stream>>>(esrc, edst, pos, offs, csr);
  k_lin_in<<<(NN + 127) / 128, 256, 0, stream>>>(x, wt, bin, h0);

  unsigned short* hs[4] = {h0, h1, h2, h3};
  for (int i = 0; i < 3; i++) {
    k_agg<<<2048, 256, 0, stream>>>(hs[i], csr, offs, dinv, agg);
    k_layer<<<(NN + 127) / 128, 256, 0, stream>>>(hs[i], agg, wt + (1 + i) * 16384,
                                                  wt + (4 + i) * 16384, bl + i * HID, hs[i + 1]);
  }
  k_cls<<<(NN + 127) / 128, 256, 0, stream>>>(h1, h2, h3, wt + 7 * 16384, bc1,
                                              wt + 8 * 16384, bc2, out);
}